// Round 8
// baseline (140.875 us; speedup 1.0000x reference)
//
#include <hip/hip_runtime.h>

#define BATCH  4096
#define NROWS  8192
#define LATENT 2048
#define ZDIM   128
#define PRIORc       0.3f
#define PRIOR_PRIMEc 0.5f

#define NSIM 2080   // 64*65/2 upper-triangle 128x128 tiles

typedef __attribute__((ext_vector_type(8))) short bf16x8;  // 8 bf16 = 4 VGPRs
typedef __attribute__((ext_vector_type(4))) float f32x4;   // MFMA C/D

__device__ inline unsigned short f2bf_rne(float f) {
    unsigned int u = __float_as_uint(f);
    u = u + 0x7fffu + ((u >> 16) & 1u);
    return (unsigned short)(u >> 16);
}

__device__ inline float wave_reduce_sum(float v) {
#pragma unroll
    for (int m = 1; m < 64; m <<= 1) v += __shfl_xor(v, m, 64);
    return v;
}

// async global->LDS, 16B per lane (dest = wave-uniform base + lane*16)
__device__ inline void gload_lds16(const void* g, void* l) {
    __builtin_amdgcn_global_load_lds(
        (const __attribute__((address_space(1))) unsigned int*)g,
        (__attribute__((address_space(3))) unsigned int*)l, 16, 0, 0);
}

// ZSCALE = sqrt(2 * log2(e)). Folds BOTH 1/TEMP and the exp->exp2 base change
// into the bf16 fragments: MFMA then yields sim*log2(e), so the sim epilogue
// is a single native v_exp_f32 (exp2) per element.
#define ZSCALE 1.69864464f

// ---------------------------------------------------------------------------
// zprep: normalize, scale by ZSCALE, cast bf16, store MFMA-swizzled; exact
// fp32 positive logit; exact bf16 diagonal dexp; zero S_row.
// ---------------------------------------------------------------------------
__global__ void k_zprep(const float* __restrict__ z_i, const float* __restrict__ z_j,
                        unsigned short* __restrict__ znb, float* __restrict__ pos,
                        float* __restrict__ dexp, float* __restrict__ S_row) {
    int bid = blockIdx.x;
    int wave = threadIdx.x >> 6, lane = threadIdx.x & 63;
    if (threadIdx.x < 8) S_row[bid * 8 + threadIdx.x] = 0.f;
    int r = bid * 4 + wave;               // 0..4095
    int p = r + BATCH;
    float2 a = ((const float2*)(z_i + (size_t)r * ZDIM))[lane];
    float2 c = ((const float2*)(z_j + (size_t)r * ZDIM))[lane];
    float sa = wave_reduce_sum(a.x * a.x + a.y * a.y);
    float sc = wave_reduce_sum(c.x * c.x + c.y * c.y);
    float dd = wave_reduce_sum(a.x * c.x + a.y * c.y);
    float inva = 1.f / fmaxf(sqrtf(sa), 1e-8f);
    float invc = 1.f / fmaxf(sqrtf(sc), 1e-8f);
    if (lane == 0) {
        float pv = 2.0f * dd * inva * invc;   // cos-sim / TEMP, exact fp32
        pos[r] = pv;
        pos[p] = pv;
    }
    int kt = lane >> 4;
    int q  = (lane >> 2) & 3;
    int j  = (lane & 3) * 2;
    int lrow = q * 16;
    float fa = inva * ZSCALE, fc = invc * ZSCALE;
    ushort2 wa; wa.x = f2bf_rne(a.x * fa); wa.y = f2bf_rne(a.y * fa);
    ushort2 wc; wc.x = f2bf_rne(c.x * fc); wc.y = f2bf_rne(c.y * fc);
    {   // row r (from z_i)
        size_t off = ((size_t)((r >> 4) * 4 + kt) * 64 + (lrow + (r & 15))) * 8 + j;
        *(ushort2*)(znb + off) = wa;
    }
    {   // row p (from z_j)
        size_t off = ((size_t)((p >> 4) * 4 + kt) * 64 + (lrow + (p & 15))) * 8 + j;
        *(ushort2*)(znb + off) = wc;
    }
    // diagonal of the bf16 sim matrix, fp32-accumulated like MFMA does
    float ax = __uint_as_float((unsigned)wa.x << 16);
    float ay = __uint_as_float((unsigned)wa.y << 16);
    float cx = __uint_as_float((unsigned)wc.x << 16);
    float cy = __uint_as_float((unsigned)wc.y << 16);
    float da = wave_reduce_sum(ax * ax + ay * ay);
    float dc = wave_reduce_sum(cx * cx + cy * cy);
    if (lane == 0) {
        dexp[r] = __builtin_amdgcn_exp2f(da);
        dexp[p] = __builtin_amdgcn_exp2f(dc);
    }
}

// ---------------------------------------------------------------------------
// Sim kernel, STANDALONE (split from the fused k_main as a controlled
// experiment: R6/R7 fused ~40us but rocprof's top-5 hid its counters, and we
// can't attribute the ~25us excess between "sim slow" and "GEMV trickling at
// sim-retirement rate under the (256,3) occupancy cap". Split gives each
// phase its own counter row and lets GEMV run at full occupancy.)
// Body unchanged from R7: B panel (contiguous 32KB of swizzled znb) bulk-
// staged to LDS via global_load_lds w=16; A frags register-resident; nt loop
// has NO global loads. __launch_bounds__(256,3): proven spill-free envelope
// (R2: (256,4) spilled fragments, 5x loss).
// ---------------------------------------------------------------------------
__global__ void __launch_bounds__(256, 3) k_sim(
        const unsigned short* __restrict__ znb, float* __restrict__ S_row) {
    int k = blockIdx.x;                       // 0..2079 upper-tri tile id
    int lane = threadIdx.x & 63, wave = threadIdx.x >> 6;
    // map k -> (i,j), i<=j: T(i) = i*(129-i)/2 tiles before row i
    int i = (int)((129.0f - sqrtf(16641.0f - 8.0f * (float)k)) * 0.5f);
    if (i > 63) i = 63;
    while (i * (129 - i) / 2 > k) --i;
    while ((i + 1) * (128 - i) / 2 <= k) ++i;
    int j = i + (k - i * (129 - i) / 2);
    bool diag = (i == j);

    int q = lane >> 4, t = lane & 15;
    int row0 = i * 128 + (wave >> 1) * 64;
    int gA = row0 >> 4;

    __shared__ __align__(16) unsigned char bpan[32768];  // B panel j (32KB)
    __shared__ float red[256];            // [0,128) rows, [128,256) cols
    red[threadIdx.x] = 0.f;

    // bulk async stage of B panel: znb[j*32KB .. +32KB) -> bpan, linear.
    {
        const unsigned char* gsrc = (const unsigned char*)znb + (size_t)j * 32768;
#pragma unroll
        for (int u = 0; u < 8; ++u) {
            int boff = u * 4096 + wave * 1024 + lane * 16;
            gload_lds16(gsrc + boff, bpan + u * 4096 + wave * 1024);
        }
    }

    // A fragments -> registers (independent of LDS staging)
    const bf16x8* zf = (const bf16x8*)znb;
    bf16x8 a[4][4];
#pragma unroll
    for (int mt = 0; mt < 4; ++mt)
#pragma unroll
        for (int kt = 0; kt < 4; ++kt)
            a[mt][kt] = zf[(size_t)((gA + mt) * 4 + kt) * 64 + lane];

    float s[16];
#pragma unroll
    for (int idx = 0; idx < 16; ++idx) s[idx] = 0.f;
    float c[4];

    __syncthreads();   // drains vmcnt(0): staging + red-zero both visible

#pragma unroll
    for (int nt = 0; nt < 4; ++nt) {
        // B fragments from LDS: local chunk ((wave&1)*4+nt)*4+kt, 1KB each
        bf16x8 b[4];
#pragma unroll
        for (int kt = 0; kt < 4; ++kt)
            b[kt] = *(const bf16x8*)(bpan +
                    ((size_t)(((wave & 1) * 4 + nt) * 4 + kt) * 1024) + lane * 16);
        f32x4 acc[4];
        f32x4 zero = {0.f, 0.f, 0.f, 0.f};
#pragma unroll
        for (int mt = 0; mt < 4; ++mt) acc[mt] = zero;
#pragma unroll
        for (int kt = 0; kt < 4; ++kt)
#pragma unroll
            for (int mt = 0; mt < 4; ++mt)
                acc[mt] = __builtin_amdgcn_mfma_f32_16x16x32_bf16(a[mt][kt], b[kt], acc[mt], 0, 0, 0);
        float csum = 0.f;
#pragma unroll
        for (int mt = 0; mt < 4; ++mt)
#pragma unroll
            for (int reg = 0; reg < 4; ++reg) {
                float e = __builtin_amdgcn_exp2f(acc[mt][reg]);
                s[mt * 4 + reg] += e;
                csum += e;
            }
        c[nt] = csum;
    }

    // row sums: reduce over t (16 lanes within q-group) -> LDS
#pragma unroll
    for (int idx = 0; idx < 16; ++idx) {
        float v = s[idx];
        v += __shfl_xor(v, 1, 64);
        v += __shfl_xor(v, 2, 64);
        v += __shfl_xor(v, 4, 64);
        v += __shfl_xor(v, 8, 64);
        if (t == 0)
            atomicAdd(&red[(wave >> 1) * 64 + (idx >> 2) * 16 + q * 4 + (idx & 3)], v);
    }
    // col sums: reduce over q (xor 16,32) -> LDS
#pragma unroll
    for (int nt = 0; nt < 4; ++nt) {
        float v = c[nt];
        v += __shfl_xor(v, 16, 64);
        v += __shfl_xor(v, 32, 64);
        if (q == 0)
            atomicAdd(&red[128 + (wave & 1) * 64 + nt * 16 + t], v);
    }
    __syncthreads();
    if (threadIdx.x < 128) {
        atomicAdd(&S_row[i * 128 + threadIdx.x], red[threadIdx.x]);
    } else if (!diag) {
        atomicAdd(&S_row[j * 128 + (threadIdx.x & 127)], red[threadIdx.x]);
    }
}

// ---------------------------------------------------------------------------
// Logit GEMV, STANDALONE at full occupancy (no launch bounds, ~20 VGPR body
// -> many waves/CU): 64MB h-stream at wire speed instead of trickling in at
// sim-block-retirement rate under the sim kernel's occupancy cap.
// ---------------------------------------------------------------------------
__global__ void k_gemv(const float* __restrict__ h_i, const float* __restrict__ h_j,
                       const float* __restrict__ W, const float* __restrict__ bb,
                       float* __restrict__ logits) {
    int lane = threadIdx.x & 63, wave = threadIdx.x >> 6;
    int r = blockIdx.x * 4 + wave;            // 0..8191
    const float* h = (r < BATCH) ? (h_i + (size_t)r * LATENT)
                                 : (h_j + (size_t)(r - BATCH) * LATENT);
    const f32x4* h4 = (const f32x4*)h;
    const f32x4* w4 = (const f32x4*)W;
    float s = 0.f;
#pragma unroll
    for (int itr = 0; itr < 8; ++itr) {
        f32x4 av = h4[itr * 64 + lane];
        f32x4 wv = w4[itr * 64 + lane];
        s += av.x * wv.x + av.y * wv.y + av.z * wv.z + av.w * wv.w;
    }
    s = wave_reduce_sum(s);
    if (lane == 0) logits[r] = s + bb[0];
}

// Single block: nnPU risk from logits+target, NT-Xent sum from
// S_row (minus exact diagonal dexp) + pos, weighted combine.
__global__ void k_final(const float* __restrict__ S_row, const float* __restrict__ pos,
                        const float* __restrict__ dexp, const float* __restrict__ logits,
                        const int* __restrict__ target,
                        const float* __restrict__ w_onnpu, float* __restrict__ out) {
    float nt_s = 0.f;
    for (int r = threadIdx.x; r < NROWS; r += 1024)
        nt_s += __logf(S_row[r] - dexp[r]) - pos[r];
    float v[8];
#pragma unroll
    for (int i = 0; i < 8; ++i) v[i] = 0.f;
    for (int r = threadIdx.x; r < BATCH; r += 1024) {
        float li = logits[r], lj = logits[BATCH + r];
        bool p = (target[r] == 1);
        float si_n = 1.f / (1.f + __expf(li));
        float si_p = 1.f / (1.f + __expf(-li));
        float sj_n = 1.f / (1.f + __expf(lj));
        float sj_p = 1.f / (1.f + __expf(-lj));
        v[0] += p ? 1.f : 0.f;
        v[1] += p ? 0.f : 1.f;
        v[2] += p ? si_n : 0.f;
        v[3] += p ? si_p : 0.f;
        v[4] += p ? 0.f : si_p;
        v[5] += p ? sj_n : 0.f;
        v[6] += p ? sj_p : 0.f;
        v[7] += p ? 0.f : sj_p;
    }
    __shared__ float red[16][9];
    int wave = threadIdx.x >> 6, lane = threadIdx.x & 63;
    nt_s = wave_reduce_sum(nt_s);
#pragma unroll
    for (int i = 0; i < 8; ++i) v[i] = wave_reduce_sum(v[i]);
    if (lane == 0) {
        red[wave][0] = nt_s;
#pragma unroll
        for (int i = 0; i < 8; ++i) red[wave][1 + i] = v[i];
    }
    __syncthreads();
    if (threadIdx.x == 0) {
        float t[9];
#pragma unroll
        for (int i = 0; i < 9; ++i) {
            float acc = 0.f;
#pragma unroll
            for (int wv = 0; wv < 16; ++wv) acc += red[wv][i];
            t[i] = acc;
        }
        float ntxent = t[0] / (float)NROWS;
        float np = fmaxf(1.f, t[1]), nu = fmaxf(1.f, t[2]);
        float pr_i = PRIOR_PRIMEc / np * t[3];
        float nr_i = (1.f - PRIOR_PRIMEc) / (nu * (1.f - PRIORc)) * t[5]
                   - (1.f - PRIOR_PRIMEc) * PRIORc / (np * (1.f - PRIORc)) * t[4];
        float li_loss = (nr_i < 0.f) ? -nr_i : (pr_i + nr_i);
        float pr_j = PRIOR_PRIMEc / np * t[6];
        float nr_j = (1.f - PRIOR_PRIMEc) / (nu * (1.f - PRIORc)) * t[8]
                   - (1.f - PRIOR_PRIMEc) * PRIORc / (np * (1.f - PRIORc)) * t[7];
        float lj_loss = (nr_j < 0.f) ? -nr_j : (pr_j + nr_j);
        float onnpu = 0.5f * (li_loss + lj_loss);
        float w = w_onnpu[0];
        out[0] = w * onnpu + (1.f - w) * ntxent;
    }
}

extern "C" void kernel_launch(void* const* d_in, const int* in_sizes, int n_in,
                              void* d_out, int out_size, void* d_ws, size_t ws_size,
                              hipStream_t stream) {
    const float* h_i = (const float*)d_in[0];
    const float* h_j = (const float*)d_in[1];
    const float* z_i = (const float*)d_in[2];
    const float* z_j = (const float*)d_in[3];
    const int* target = (const int*)d_in[4];
    const float* W = (const float*)d_in[5];
    const float* b = (const float*)d_in[6];
    const float* w_onnpu = (const float*)d_in[7];

    char* ws = (char*)d_ws;
    unsigned short* znb = (unsigned short*)ws;              // 2 MB swizzled bf16
    float* S_row  = (float*)(ws + 2097152);                 // 32 KB
    float* pos    = (float*)(ws + 2097152 + 32768);         // 32 KB
    float* logits = (float*)(ws + 2097152 + 65536);         // 32 KB
    float* dexp   = (float*)(ws + 2097152 + 98304);         // 32 KB
    float* out = (float*)d_out;

    k_zprep<<<1024, 256, 0, stream>>>(z_i, z_j, znb, pos, dexp, S_row);
    k_sim<<<NSIM, 256, 0, stream>>>(znb, S_row);
    k_gemv<<<2048, 256, 0, stream>>>(h_i, h_j, W, b, logits);
    k_final<<<1, 1024, 0, stream>>>(S_row, pos, dexp, logits, target, w_onnpu, out);
}

// Round 9
// 136.072 us; speedup vs baseline: 1.0353x; 1.0353x over previous
//
#include <hip/hip_runtime.h>

#define BATCH  4096
#define NROWS  8192
#define LATENT 2048
#define ZDIM   128
#define PRIORc       0.3f
#define PRIOR_PRIMEc 0.5f

#define NSIM 2080   // 64*65/2 upper-triangle 128x128 tiles
#define NREP 16     // S_row accumulator replicas (atomic de-contention)

typedef __attribute__((ext_vector_type(8))) short bf16x8;  // 8 bf16 = 4 VGPRs
typedef __attribute__((ext_vector_type(4))) float f32x4;   // MFMA C/D

__device__ inline unsigned short f2bf_rne(float f) {
    unsigned int u = __float_as_uint(f);
    u = u + 0x7fffu + ((u >> 16) & 1u);
    return (unsigned short)(u >> 16);
}

__device__ inline float wave_reduce_sum(float v) {
#pragma unroll
    for (int m = 1; m < 64; m <<= 1) v += __shfl_xor(v, m, 64);
    return v;
}

// async global->LDS, 16B per lane (dest = wave-uniform base + lane*16)
__device__ inline void gload_lds16(const void* g, void* l) {
    __builtin_amdgcn_global_load_lds(
        (const __attribute__((address_space(1))) unsigned int*)g,
        (__attribute__((address_space(3))) unsigned int*)l, 16, 0, 0);
}

// ZSCALE = sqrt(2 * log2(e)). Folds BOTH 1/TEMP and the exp->exp2 base change
// into the bf16 fragments: MFMA then yields sim*log2(e), so the sim epilogue
// is a single native v_exp_f32 (exp2) per element.
#define ZSCALE 1.69864464f

// ---------------------------------------------------------------------------
// zprep: normalize, scale by ZSCALE, cast bf16, store MFMA-swizzled; exact
// fp32 positive logit; exact bf16 diagonal dexp; zero the 512KB S_rep bank.
// ---------------------------------------------------------------------------
__global__ void k_zprep(const float* __restrict__ z_i, const float* __restrict__ z_j,
                        unsigned short* __restrict__ znb, float* __restrict__ pos,
                        float* __restrict__ dexp, float* __restrict__ S_rep) {
    int bid = blockIdx.x;
    int wave = threadIdx.x >> 6, lane = threadIdx.x & 63;
    {   // zero S_rep: NREP*NROWS floats = 65536 float2; grid has 262144 threads
        int g = bid * 256 + threadIdx.x;
        if (g < NREP * NROWS / 2) {
            float2 zz; zz.x = 0.f; zz.y = 0.f;
            ((float2*)S_rep)[g] = zz;
        }
    }
    int r = bid * 4 + wave;               // 0..4095
    int p = r + BATCH;
    float2 a = ((const float2*)(z_i + (size_t)r * ZDIM))[lane];
    float2 c = ((const float2*)(z_j + (size_t)r * ZDIM))[lane];
    float sa = wave_reduce_sum(a.x * a.x + a.y * a.y);
    float sc = wave_reduce_sum(c.x * c.x + c.y * c.y);
    float dd = wave_reduce_sum(a.x * c.x + a.y * c.y);
    float inva = 1.f / fmaxf(sqrtf(sa), 1e-8f);
    float invc = 1.f / fmaxf(sqrtf(sc), 1e-8f);
    if (lane == 0) {
        float pv = 2.0f * dd * inva * invc;   // cos-sim / TEMP, exact fp32
        pos[r] = pv;
        pos[p] = pv;
    }
    int kt = lane >> 4;
    int q  = (lane >> 2) & 3;
    int j  = (lane & 3) * 2;
    int lrow = q * 16;
    float fa = inva * ZSCALE, fc = invc * ZSCALE;
    ushort2 wa; wa.x = f2bf_rne(a.x * fa); wa.y = f2bf_rne(a.y * fa);
    ushort2 wc; wc.x = f2bf_rne(c.x * fc); wc.y = f2bf_rne(c.y * fc);
    {   // row r (from z_i)
        size_t off = ((size_t)((r >> 4) * 4 + kt) * 64 + (lrow + (r & 15))) * 8 + j;
        *(ushort2*)(znb + off) = wa;
    }
    {   // row p (from z_j)
        size_t off = ((size_t)((p >> 4) * 4 + kt) * 64 + (lrow + (p & 15))) * 8 + j;
        *(ushort2*)(znb + off) = wc;
    }
    // diagonal of the bf16 sim matrix, fp32-accumulated like MFMA does
    float ax = __uint_as_float((unsigned)wa.x << 16);
    float ay = __uint_as_float((unsigned)wa.y << 16);
    float cx = __uint_as_float((unsigned)wc.x << 16);
    float cy = __uint_as_float((unsigned)wc.y << 16);
    float da = wave_reduce_sum(ax * ax + ay * ay);
    float dc = wave_reduce_sum(cx * cx + cy * cy);
    if (lane == 0) {
        dexp[r] = __builtin_amdgcn_exp2f(da);
        dexp[p] = __builtin_amdgcn_exp2f(dc);
    }
}

// ---------------------------------------------------------------------------
// Main kernel, FUSED (R8 split experiment measured fusion worth +7.5us).
// bids [0,NSIM) = symmetric-half sim tiles; bids >= NSIM = logit GEMV which
// backfills CUs as sim blocks retire (overlapping sim's tail).
//
// ATOMIC DE-CONTENTION (R9 change): R1/R4/R7/R8 runtimes were insensitive to
// the amount of MFMA/exp work — the dominant cost fits 532K device-scope fp32
// atomicAdds onto S_row's 256 cache lines (2080 serialized ops/line at the
// L3 coherence point ~= 15-25us that occupancy cannot hide). Each block now
// atomics into replica (bid & 15) of S_rep[16][8192] -> 16x less per-line
// serialization; k_final sums the replicas.
// Sim body otherwise unchanged from R7: B panel (contiguous 32KB of swizzled
// znb) bulk-staged to LDS via global_load_lds w=16; A frags register-
// resident; nt loop has NO global loads. __launch_bounds__(256,3): proven
// spill-free envelope (R2: (256,4) spilled fragments, 5x loss).
// ---------------------------------------------------------------------------
__global__ void __launch_bounds__(256, 3) k_main(
        const unsigned short* __restrict__ znb, float* __restrict__ S_rep,
        const float* __restrict__ h_i, const float* __restrict__ h_j,
        const float* __restrict__ W, const float* __restrict__ bb,
        float* __restrict__ logits) {
    int bid = blockIdx.x;
    int lane = threadIdx.x & 63, wave = threadIdx.x >> 6;
    if (bid < NSIM) {
        int k = bid;                          // 0..2079 upper-tri tile id
        // map k -> (i,j), i<=j: T(i) = i*(129-i)/2 tiles before row i
        int i = (int)((129.0f - sqrtf(16641.0f - 8.0f * (float)k)) * 0.5f);
        if (i > 63) i = 63;
        while (i * (129 - i) / 2 > k) --i;
        while ((i + 1) * (128 - i) / 2 <= k) ++i;
        int j = i + (k - i * (129 - i) / 2);
        bool diag = (i == j);
        float* Sr = S_rep + (size_t)(bid & (NREP - 1)) * NROWS;

        int q = lane >> 4, t = lane & 15;
        int row0 = i * 128 + (wave >> 1) * 64;
        int gA = row0 >> 4;

        __shared__ __align__(16) unsigned char bpan[32768];  // B panel j (32KB)
        __shared__ float red[256];            // [0,128) rows, [128,256) cols
        red[threadIdx.x] = 0.f;

        // bulk async stage of B panel: znb[j*32KB .. +32KB) -> bpan, linear.
        {
            const unsigned char* gsrc = (const unsigned char*)znb + (size_t)j * 32768;
#pragma unroll
            for (int u = 0; u < 8; ++u) {
                int boff = u * 4096 + wave * 1024 + lane * 16;
                gload_lds16(gsrc + boff, bpan + u * 4096 + wave * 1024);
            }
        }

        // A fragments -> registers (independent of LDS staging)
        const bf16x8* zf = (const bf16x8*)znb;
        bf16x8 a[4][4];
#pragma unroll
        for (int mt = 0; mt < 4; ++mt)
#pragma unroll
            for (int kt = 0; kt < 4; ++kt)
                a[mt][kt] = zf[(size_t)((gA + mt) * 4 + kt) * 64 + lane];

        float s[16];
#pragma unroll
        for (int idx = 0; idx < 16; ++idx) s[idx] = 0.f;
        float c[4];

        __syncthreads();   // drains vmcnt(0): staging + red-zero both visible

#pragma unroll
        for (int nt = 0; nt < 4; ++nt) {
            // B fragments from LDS: local chunk ((wave&1)*4+nt)*4+kt, 1KB each
            bf16x8 b[4];
#pragma unroll
            for (int kt = 0; kt < 4; ++kt)
                b[kt] = *(const bf16x8*)(bpan +
                        ((size_t)(((wave & 1) * 4 + nt) * 4 + kt) * 1024) + lane * 16);
            f32x4 acc[4];
            f32x4 zero = {0.f, 0.f, 0.f, 0.f};
#pragma unroll
            for (int mt = 0; mt < 4; ++mt) acc[mt] = zero;
#pragma unroll
            for (int kt = 0; kt < 4; ++kt)
#pragma unroll
                for (int mt = 0; mt < 4; ++mt)
                    acc[mt] = __builtin_amdgcn_mfma_f32_16x16x32_bf16(a[mt][kt], b[kt], acc[mt], 0, 0, 0);
            float csum = 0.f;
#pragma unroll
            for (int mt = 0; mt < 4; ++mt)
#pragma unroll
                for (int reg = 0; reg < 4; ++reg) {
                    float e = __builtin_amdgcn_exp2f(acc[mt][reg]);
                    s[mt * 4 + reg] += e;
                    csum += e;
                }
            c[nt] = csum;
        }

        // row sums: reduce over t (16 lanes within q-group) -> LDS
#pragma unroll
        for (int idx = 0; idx < 16; ++idx) {
            float v = s[idx];
            v += __shfl_xor(v, 1, 64);
            v += __shfl_xor(v, 2, 64);
            v += __shfl_xor(v, 4, 64);
            v += __shfl_xor(v, 8, 64);
            if (t == 0)
                atomicAdd(&red[(wave >> 1) * 64 + (idx >> 2) * 16 + q * 4 + (idx & 3)], v);
        }
        // col sums: reduce over q (xor 16,32) -> LDS
#pragma unroll
        for (int nt = 0; nt < 4; ++nt) {
            float v = c[nt];
            v += __shfl_xor(v, 16, 64);
            v += __shfl_xor(v, 32, 64);
            if (q == 0)
                atomicAdd(&red[128 + (wave & 1) * 64 + nt * 16 + t], v);
        }
        __syncthreads();
        if (threadIdx.x < 128) {
            atomicAdd(&Sr[i * 128 + threadIdx.x], red[threadIdx.x]);
        } else if (!diag) {
            atomicAdd(&Sr[j * 128 + (threadIdx.x & 127)], red[threadIdx.x]);
        }
    } else {
        int r = (bid - NSIM) * 4 + wave;      // 0..8191
        const float* h = (r < BATCH) ? (h_i + (size_t)r * LATENT)
                                     : (h_j + (size_t)(r - BATCH) * LATENT);
        const f32x4* h4 = (const f32x4*)h;
        const f32x4* w4 = (const f32x4*)W;
        float s = 0.f;
#pragma unroll
        for (int itr = 0; itr < 8; ++itr) {
            f32x4 av = h4[itr * 64 + lane];
            f32x4 wv = w4[itr * 64 + lane];
            s += av.x * wv.x + av.y * wv.y + av.z * wv.z + av.w * wv.w;
        }
        s = wave_reduce_sum(s);
        if (lane == 0) logits[r] = s + bb[0];
    }
}

// Single block: nnPU risk from logits+target, NT-Xent sum from
// sum-of-replicas S_rep (minus exact diagonal dexp) + pos, weighted combine.
__global__ void k_final(const float* __restrict__ S_rep, const float* __restrict__ pos,
                        const float* __restrict__ dexp, const float* __restrict__ logits,
                        const int* __restrict__ target,
                        const float* __restrict__ w_onnpu, float* __restrict__ out) {
    float nt_s = 0.f;
    for (int r = threadIdx.x; r < NROWS; r += 1024) {
        float sv = 0.f;
#pragma unroll
        for (int rep = 0; rep < NREP; ++rep)
            sv += S_rep[(size_t)rep * NROWS + r];
        nt_s += __logf(sv - dexp[r]) - pos[r];
    }
    float v[8];
#pragma unroll
    for (int i = 0; i < 8; ++i) v[i] = 0.f;
    for (int r = threadIdx.x; r < BATCH; r += 1024) {
        float li = logits[r], lj = logits[BATCH + r];
        bool p = (target[r] == 1);
        float si_n = 1.f / (1.f + __expf(li));
        float si_p = 1.f / (1.f + __expf(-li));
        float sj_n = 1.f / (1.f + __expf(lj));
        float sj_p = 1.f / (1.f + __expf(-lj));
        v[0] += p ? 1.f : 0.f;
        v[1] += p ? 0.f : 1.f;
        v[2] += p ? si_n : 0.f;
        v[3] += p ? si_p : 0.f;
        v[4] += p ? 0.f : si_p;
        v[5] += p ? sj_n : 0.f;
        v[6] += p ? sj_p : 0.f;
        v[7] += p ? 0.f : sj_p;
    }
    __shared__ float red[16][9];
    int wave = threadIdx.x >> 6, lane = threadIdx.x & 63;
    nt_s = wave_reduce_sum(nt_s);
#pragma unroll
    for (int i = 0; i < 8; ++i) v[i] = wave_reduce_sum(v[i]);
    if (lane == 0) {
        red[wave][0] = nt_s;
#pragma unroll
        for (int i = 0; i < 8; ++i) red[wave][1 + i] = v[i];
    }
    __syncthreads();
    if (threadIdx.x == 0) {
        float t[9];
#pragma unroll
        for (int i = 0; i < 9; ++i) {
            float acc = 0.f;
#pragma unroll
            for (int wv = 0; wv < 16; ++wv) acc += red[wv][i];
            t[i] = acc;
        }
        float ntxent = t[0] / (float)NROWS;
        float np = fmaxf(1.f, t[1]), nu = fmaxf(1.f, t[2]);
        float pr_i = PRIOR_PRIMEc / np * t[3];
        float nr_i = (1.f - PRIOR_PRIMEc) / (nu * (1.f - PRIORc)) * t[5]
                   - (1.f - PRIOR_PRIMEc) * PRIORc / (np * (1.f - PRIORc)) * t[4];
        float li_loss = (nr_i < 0.f) ? -nr_i : (pr_i + nr_i);
        float pr_j = PRIOR_PRIMEc / np * t[6];
        float nr_j = (1.f - PRIOR_PRIMEc) / (nu * (1.f - PRIORc)) * t[8]
                   - (1.f - PRIOR_PRIMEc) * PRIORc / (np * (1.f - PRIORc)) * t[7];
        float lj_loss = (nr_j < 0.f) ? -nr_j : (pr_j + nr_j);
        float onnpu = 0.5f * (li_loss + lj_loss);
        float w = w_onnpu[0];
        out[0] = w * onnpu + (1.f - w) * ntxent;
    }
}

extern "C" void kernel_launch(void* const* d_in, const int* in_sizes, int n_in,
                              void* d_out, int out_size, void* d_ws, size_t ws_size,
                              hipStream_t stream) {
    const float* h_i = (const float*)d_in[0];
    const float* h_j = (const float*)d_in[1];
    const float* z_i = (const float*)d_in[2];
    const float* z_j = (const float*)d_in[3];
    const int* target = (const int*)d_in[4];
    const float* W = (const float*)d_in[5];
    const float* b = (const float*)d_in[6];
    const float* w_onnpu = (const float*)d_in[7];

    char* ws = (char*)d_ws;
    unsigned short* znb = (unsigned short*)ws;              // 2 MB swizzled bf16
    float* S_rep  = (float*)(ws + 2097152);                 // 512 KB (16 replicas)
    float* pos    = (float*)(ws + 2097152 + 524288);        // 32 KB
    float* logits = (float*)(ws + 2097152 + 557056);        // 32 KB
    float* dexp   = (float*)(ws + 2097152 + 589824);        // 32 KB
    float* out = (float*)d_out;

    k_zprep<<<1024, 256, 0, stream>>>(z_i, z_j, znb, pos, dexp, S_rep);
    k_main<<<NSIM + 2048, 256, 0, stream>>>(znb, S_rep, h_i, h_j, W, b, logits);
    k_final<<<1, 1024, 0, stream>>>(S_rep, pos, dexp, logits, target, w_onnpu, out);
}

// Round 11
// 132.120 us; speedup vs baseline: 1.0663x; 1.0299x over previous
//
#include <hip/hip_runtime.h>

#define BATCH  4096
#define NROWS  8192
#define LATENT 2048
#define ZDIM   128
#define PRIORc       0.3f
#define PRIOR_PRIMEc 0.5f

#define NSIM 2080   // 64*65/2 upper-triangle 128x128 tiles

typedef __attribute__((ext_vector_type(8))) short bf16x8;  // 8 bf16 = 4 VGPRs
typedef __attribute__((ext_vector_type(4))) float f32x4;   // MFMA C/D

__device__ inline unsigned short f2bf_rne(float f) {
    unsigned int u = __float_as_uint(f);
    u = u + 0x7fffu + ((u >> 16) & 1u);
    return (unsigned short)(u >> 16);
}

__device__ inline float wave_reduce_sum(float v) {
#pragma unroll
    for (int m = 1; m < 64; m <<= 1) v += __shfl_xor(v, m, 64);
    return v;
}

// async global->LDS, 16B per lane (dest = wave-uniform base + lane*16)
__device__ inline void gload_lds16(const void* g, void* l) {
    __builtin_amdgcn_global_load_lds(
        (const __attribute__((address_space(1))) unsigned int*)g,
        (__attribute__((address_space(3))) unsigned int*)l, 16, 0, 0);
}

// ZSCALE = sqrt(2 * log2(e)). Folds BOTH 1/TEMP and the exp->exp2 base change
// into the bf16 fragments: MFMA then yields sim*log2(e), so the sim epilogue
// is a single native v_exp_f32 (exp2) per element.
#define ZSCALE 1.69864464f

// ---------------------------------------------------------------------------
// zprep: normalize, scale by ZSCALE, cast bf16, store MFMA-swizzled; exact
// fp32 positive logit; exact bf16 diagonal dexp; zero S_row.
// NOTE (R10): single-coop-kernel fusion FAILED — hipLaunchCooperativeKernel
// is not graph-capturable (out stayed 0), and grid.sync() lacks the L2
// writeback/invalidate that kernel boundaries provide (poison-filled stale
// lines in remote XCD L2s). Keep the multi-kernel structure.
// ---------------------------------------------------------------------------
__global__ void k_zprep(const float* __restrict__ z_i, const float* __restrict__ z_j,
                        unsigned short* __restrict__ znb, float* __restrict__ pos,
                        float* __restrict__ dexp, float* __restrict__ S_row) {
    int bid = blockIdx.x;
    int wave = threadIdx.x >> 6, lane = threadIdx.x & 63;
    if (threadIdx.x < 8) S_row[bid * 8 + threadIdx.x] = 0.f;
    int r = bid * 4 + wave;               // 0..4095
    int p = r + BATCH;
    float2 a = ((const float2*)(z_i + (size_t)r * ZDIM))[lane];
    float2 c = ((const float2*)(z_j + (size_t)r * ZDIM))[lane];
    float sa = wave_reduce_sum(a.x * a.x + a.y * a.y);
    float sc = wave_reduce_sum(c.x * c.x + c.y * c.y);
    float dd = wave_reduce_sum(a.x * c.x + a.y * c.y);
    float inva = 1.f / fmaxf(sqrtf(sa), 1e-8f);
    float invc = 1.f / fmaxf(sqrtf(sc), 1e-8f);
    if (lane == 0) {
        float pv = 2.0f * dd * inva * invc;   // cos-sim / TEMP, exact fp32
        pos[r] = pv;
        pos[p] = pv;
    }
    int kt = lane >> 4;
    int q  = (lane >> 2) & 3;
    int j  = (lane & 3) * 2;
    int lrow = q * 16;
    float fa = inva * ZSCALE, fc = invc * ZSCALE;
    ushort2 wa; wa.x = f2bf_rne(a.x * fa); wa.y = f2bf_rne(a.y * fa);
    ushort2 wc; wc.x = f2bf_rne(c.x * fc); wc.y = f2bf_rne(c.y * fc);
    {   // row r (from z_i)
        size_t off = ((size_t)((r >> 4) * 4 + kt) * 64 + (lrow + (r & 15))) * 8 + j;
        *(ushort2*)(znb + off) = wa;
    }
    {   // row p (from z_j)
        size_t off = ((size_t)((p >> 4) * 4 + kt) * 64 + (lrow + (p & 15))) * 8 + j;
        *(ushort2*)(znb + off) = wc;
    }
    // diagonal of the bf16 sim matrix, fp32-accumulated like MFMA does
    float ax = __uint_as_float((unsigned)wa.x << 16);
    float ay = __uint_as_float((unsigned)wa.y << 16);
    float cx = __uint_as_float((unsigned)wc.x << 16);
    float cy = __uint_as_float((unsigned)wc.y << 16);
    float da = wave_reduce_sum(ax * ax + ay * ay);
    float dc = wave_reduce_sum(cx * cx + cy * cy);
    if (lane == 0) {
        dexp[r] = __builtin_amdgcn_exp2f(da);
        dexp[p] = __builtin_amdgcn_exp2f(dc);
    }
}

// ---------------------------------------------------------------------------
// Main kernel. bids [0,NSIM) = symmetric-half sim tiles; bids >= NSIM = logit
// GEMV backfilling sim's drain tail (R8 measured the fused-ordered structure
// worth +7.5us vs split).
//
// R11 change: __launch_bounds__(256,4). Surviving theory after 5
// falsifications (striping R1, B-latency R7, atomics R9, coop R10): sim is
// latency-bound at ~8.3 waves/CU — per-wave serial chain ~5-6K cyc with only
// ~2 block-slots/CU of overlap. The R7 body (no bn prefetch, B via LDS) needs
// ~118 VGPR, so the 128 cap at 4 waves/EU should FIT now (R2's spill at
// (256,4) was the OLD body: bn[4]+global-B ~ 146 VGPR). LDS 33KB allows
// 4 blocks/CU. Expected: occupancy 26->~45%, k_main 40->~28us.
// REVERT RULE: if FETCH_SIZE balloons (>100MB) it spilled -> back to (256,3).
// ---------------------------------------------------------------------------
__global__ void __launch_bounds__(256, 4) k_main(
        const unsigned short* __restrict__ znb, float* __restrict__ S_row,
        const float* __restrict__ h_i, const float* __restrict__ h_j,
        const float* __restrict__ W, const float* __restrict__ bb,
        float* __restrict__ logits) {
    int bid = blockIdx.x;
    int lane = threadIdx.x & 63, wave = threadIdx.x >> 6;
    if (bid < NSIM) {
        int k = bid;                          // 0..2079 upper-tri tile id
        // map k -> (i,j), i<=j: T(i) = i*(129-i)/2 tiles before row i
        int i = (int)((129.0f - sqrtf(16641.0f - 8.0f * (float)k)) * 0.5f);
        if (i > 63) i = 63;
        while (i * (129 - i) / 2 > k) --i;
        while ((i + 1) * (128 - i) / 2 <= k) ++i;
        int j = i + (k - i * (129 - i) / 2);
        bool diag = (i == j);

        int q = lane >> 4, t = lane & 15;
        int row0 = i * 128 + (wave >> 1) * 64;
        int gA = row0 >> 4;

        __shared__ __align__(16) unsigned char bpan[32768];  // B panel j (32KB)
        __shared__ float red[256];            // [0,128) rows, [128,256) cols

        // bulk async stage of B panel first (earliest issue): znb[j*32KB..+32KB)
        {
            const unsigned char* gsrc = (const unsigned char*)znb + (size_t)j * 32768;
#pragma unroll
            for (int u = 0; u < 8; ++u) {
                int boff = u * 4096 + wave * 1024 + lane * 16;
                gload_lds16(gsrc + boff, bpan + u * 4096 + wave * 1024);
            }
        }
        red[threadIdx.x] = 0.f;

        // A fragments -> registers (independent of LDS staging)
        const bf16x8* zf = (const bf16x8*)znb;
        bf16x8 a[4][4];
#pragma unroll
        for (int mt = 0; mt < 4; ++mt)
#pragma unroll
            for (int kt = 0; kt < 4; ++kt)
                a[mt][kt] = zf[(size_t)((gA + mt) * 4 + kt) * 64 + lane];

        float s[16];
#pragma unroll
        for (int idx = 0; idx < 16; ++idx) s[idx] = 0.f;
        float c[4];

        __syncthreads();   // drains vmcnt(0): staging + red-zero both visible

#pragma unroll
        for (int nt = 0; nt < 4; ++nt) {
            // B fragments from LDS: local chunk ((wave&1)*4+nt)*4+kt, 1KB each
            bf16x8 b[4];
#pragma unroll
            for (int kt = 0; kt < 4; ++kt)
                b[kt] = *(const bf16x8*)(bpan +
                        ((size_t)(((wave & 1) * 4 + nt) * 4 + kt) * 1024) + lane * 16);
            f32x4 acc[4];
            f32x4 zero = {0.f, 0.f, 0.f, 0.f};
#pragma unroll
            for (int mt = 0; mt < 4; ++mt) acc[mt] = zero;
#pragma unroll
            for (int kt = 0; kt < 4; ++kt)
#pragma unroll
                for (int mt = 0; mt < 4; ++mt)
                    acc[mt] = __builtin_amdgcn_mfma_f32_16x16x32_bf16(a[mt][kt], b[kt], acc[mt], 0, 0, 0);
            float csum = 0.f;
#pragma unroll
            for (int mt = 0; mt < 4; ++mt)
#pragma unroll
                for (int reg = 0; reg < 4; ++reg) {
                    float e = __builtin_amdgcn_exp2f(acc[mt][reg]);
                    s[mt * 4 + reg] += e;
                    csum += e;
                }
            c[nt] = csum;
        }

        // row sums: reduce over t (16 lanes within q-group) -> LDS
#pragma unroll
        for (int idx = 0; idx < 16; ++idx) {
            float v = s[idx];
            v += __shfl_xor(v, 1, 64);
            v += __shfl_xor(v, 2, 64);
            v += __shfl_xor(v, 4, 64);
            v += __shfl_xor(v, 8, 64);
            if (t == 0)
                atomicAdd(&red[(wave >> 1) * 64 + (idx >> 2) * 16 + q * 4 + (idx & 3)], v);
        }
        // col sums: reduce over q (xor 16,32) -> LDS
#pragma unroll
        for (int nt = 0; nt < 4; ++nt) {
            float v = c[nt];
            v += __shfl_xor(v, 16, 64);
            v += __shfl_xor(v, 32, 64);
            if (q == 0)
                atomicAdd(&red[128 + (wave & 1) * 64 + nt * 16 + t], v);
        }
        __syncthreads();
        if (threadIdx.x < 128) {
            atomicAdd(&S_row[i * 128 + threadIdx.x], red[threadIdx.x]);
        } else if (!diag) {
            atomicAdd(&S_row[j * 128 + (threadIdx.x & 127)], red[threadIdx.x]);
        }
    } else {
        int r = (bid - NSIM) * 4 + wave;      // 0..8191
        const float* h = (r < BATCH) ? (h_i + (size_t)r * LATENT)
                                     : (h_j + (size_t)(r - BATCH) * LATENT);
        const f32x4* h4 = (const f32x4*)h;
        const f32x4* w4 = (const f32x4*)W;
        float s = 0.f;
#pragma unroll
        for (int itr = 0; itr < 8; ++itr) {
            f32x4 av = h4[itr * 64 + lane];
            f32x4 wv = w4[itr * 64 + lane];
            s += av.x * wv.x + av.y * wv.y + av.z * wv.z + av.w * wv.w;
        }
        s = wave_reduce_sum(s);
        if (lane == 0) logits[r] = s + bb[0];
    }
}

// Single block: nnPU risk from logits+target, NT-Xent sum from
// S_row (minus exact diagonal dexp) + pos, weighted combine.
__global__ void k_final(const float* __restrict__ S_row, const float* __restrict__ pos,
                        const float* __restrict__ dexp, const float* __restrict__ logits,
                        const int* __restrict__ target,
                        const float* __restrict__ w_onnpu, float* __restrict__ out) {
    float nt_s = 0.f;
    for (int r = threadIdx.x; r < NROWS; r += 1024)
        nt_s += __logf(S_row[r] - dexp[r]) - pos[r];
    float v[8];
#pragma unroll
    for (int i = 0; i < 8; ++i) v[i] = 0.f;
    for (int r = threadIdx.x; r < BATCH; r += 1024) {
        float li = logits[r], lj = logits[BATCH + r];
        bool p = (target[r] == 1);
        float si_n = 1.f / (1.f + __expf(li));
        float si_p = 1.f / (1.f + __expf(-li));
        float sj_n = 1.f / (1.f + __expf(lj));
        float sj_p = 1.f / (1.f + __expf(-lj));
        v[0] += p ? 1.f : 0.f;
        v[1] += p ? 0.f : 1.f;
        v[2] += p ? si_n : 0.f;
        v[3] += p ? si_p : 0.f;
        v[4] += p ? 0.f : si_p;
        v[5] += p ? sj_n : 0.f;
        v[6] += p ? sj_p : 0.f;
        v[7] += p ? 0.f : sj_p;
    }
    __shared__ float red[16][9];
    int wave = threadIdx.x >> 6, lane = threadIdx.x & 63;
    nt_s = wave_reduce_sum(nt_s);
#pragma unroll
    for (int i = 0; i < 8; ++i) v[i] = wave_reduce_sum(v[i]);
    if (lane == 0) {
        red[wave][0] = nt_s;
#pragma unroll
        for (int i = 0; i < 8; ++i) red[wave][1 + i] = v[i];
    }
    __syncthreads();
    if (threadIdx.x == 0) {
        float t[9];
#pragma unroll
        for (int i = 0; i < 9; ++i) {
            float acc = 0.f;
#pragma unroll
            for (int wv = 0; wv < 16; ++wv) acc += red[wv][i];
            t[i] = acc;
        }
        float ntxent = t[0] / (float)NROWS;
        float np = fmaxf(1.f, t[1]), nu = fmaxf(1.f, t[2]);
        float pr_i = PRIOR_PRIMEc / np * t[3];
        float nr_i = (1.f - PRIOR_PRIMEc) / (nu * (1.f - PRIORc)) * t[5]
                   - (1.f - PRIOR_PRIMEc) * PRIORc / (np * (1.f - PRIORc)) * t[4];
        float li_loss = (nr_i < 0.f) ? -nr_i : (pr_i + nr_i);
        float pr_j = PRIOR_PRIMEc / np * t[6];
        float nr_j = (1.f - PRIOR_PRIMEc) / (nu * (1.f - PRIORc)) * t[8]
                   - (1.f - PRIOR_PRIMEc) * PRIORc / (np * (1.f - PRIORc)) * t[7];
        float lj_loss = (nr_j < 0.f) ? -nr_j : (pr_j + nr_j);
        float onnpu = 0.5f * (li_loss + lj_loss);
        float w = w_onnpu[0];
        out[0] = w * onnpu + (1.f - w) * ntxent;
    }
}

extern "C" void kernel_launch(void* const* d_in, const int* in_sizes, int n_in,
                              void* d_out, int out_size, void* d_ws, size_t ws_size,
                              hipStream_t stream) {
    const float* h_i = (const float*)d_in[0];
    const float* h_j = (const float*)d_in[1];
    const float* z_i = (const float*)d_in[2];
    const float* z_j = (const float*)d_in[3];
    const int* target = (const int*)d_in[4];
    const float* W = (const float*)d_in[5];
    const float* b = (const float*)d_in[6];
    const float* w_onnpu = (const float*)d_in[7];

    char* ws = (char*)d_ws;
    unsigned short* znb = (unsigned short*)ws;              // 2 MB swizzled bf16
    float* S_row  = (float*)(ws + 2097152);                 // 32 KB
    float* pos    = (float*)(ws + 2097152 + 32768);         // 32 KB
    float* logits = (float*)(ws + 2097152 + 65536);         // 32 KB
    float* dexp   = (float*)(ws + 2097152 + 98304);         // 32 KB
    float* out = (float*)d_out;

    k_zprep<<<1024, 256, 0, stream>>>(z_i, z_j, znb, pos, dexp, S_row);
    k_main<<<NSIM + 2048, 256, 0, stream>>>(znb, S_row, h_i, h_j, W, b, logits);
    k_final<<<1, 1024, 0, stream>>>(S_row, pos, dexp, logits, target, w_onnpu, out);
}